// Round 11
// baseline (430.076 us; speedup 1.0000x reference)
//
#include <hip/hip_runtime.h>

#define T_LEN 2048
#define C_DIM 1024
#define PAIR_F 768          // floats per (head, step-pair) packet
#define NCH 32              // chunks
#define CPAIR 32            // pairs per chunk (NCH*CPAIR = 1024)

#define AS1 __attribute__((address_space(1)))
#define AS3 __attribute__((address_space(3)))

typedef __attribute__((ext_vector_type(8))) short bf8_t;
typedef __attribute__((ext_vector_type(4))) float f4_t;
typedef __attribute__((ext_vector_type(2))) float f2_t;

static __device__ __forceinline__ float sigf(float x) {
    return 1.f / (1.f + __expf(-x));
}
static __device__ __forceinline__ unsigned short f2bf(float f) {
    unsigned u = __float_as_uint(f);
    u += 0x7fff + ((u >> 16) & 1);
    return (unsigned short)(u >> 16);
}

// ---- cross-lane reduction helpers (defined early; used by lora2f + scans) --
static __device__ __forceinline__ float red16(float x) {
    int xi;
    xi = __builtin_amdgcn_mov_dpp(__float_as_int(x), 0x128, 0xf, 0xf, true);
    x += __int_as_float(xi);
    xi = __builtin_amdgcn_mov_dpp(__float_as_int(x), 0x124, 0xf, 0xf, true);
    x += __int_as_float(xi);
    xi = __builtin_amdgcn_mov_dpp(__float_as_int(x), 0x122, 0xf, 0xf, true);
    x += __int_as_float(xi);
    xi = __builtin_amdgcn_mov_dpp(__float_as_int(x), 0x121, 0xf, 0xf, true);
    x += __int_as_float(xi);
    return x;
}
// full 64-lane sum: DPP within 16 (VALU pipe), then only 2 DS-ops
static __device__ __forceinline__ float red64(float x) {
    x = red16(x);
    x += __shfl_xor(x, 16);
    x += __shfl_xor(x, 32);
    return x;
}

static __device__ __forceinline__ f2_t f2bc(float s) { return (f2_t){s, s}; }
static __device__ __forceinline__ f2_t fma2(f2_t a, f2_t b, f2_t c) {
    return __builtin_elementwise_fma(a, b, c);
}
static __device__ __forceinline__ f2_t lo2(const float4& v) { return (f2_t){v.x, v.y}; }
static __device__ __forceinline__ f2_t hi2(const float4& v) { return (f2_t){v.z, v.w}; }

static __device__ __forceinline__ float dot4pk(f2_t Sl, f2_t Sh, const float4& A) {
    f2_t m = Sl * lo2(A);
    m = fma2(Sh, hi2(A), m);
    return m.x + m.y;
}

// ---------------------------------------------------------------------------
// Convert the four 1024x1024 fp32 weights into one bf16 block (1M strides),
// plus the transposed LoRA stage-1 weights (blocks 4096..4383).
// ---------------------------------------------------------------------------
__global__ __launch_bounds__(256) void wcvtall(
    const float* __restrict__ Wr, const float* __restrict__ Wk,
    const float* __restrict__ Wv, const float* __restrict__ Wo,
    const float* __restrict__ w1, const float* __restrict__ a1,
    const float* __restrict__ v1, const float* __restrict__ g1,
    unsigned short* __restrict__ dst, unsigned short* __restrict__ lw16)
{
    const int b = blockIdx.x;
    if (b < 4096) {
        const size_t idx = ((size_t)b * 256 + threadIdx.x) * 4;
        const int sel = (int)(idx >> 20);
        const float* src = sel == 0 ? Wr : sel == 1 ? Wk : sel == 2 ? Wv : Wo;
        float4 v = *(const float4*)(src + (idx & 0xFFFFF));
        ushort4 o = {f2bf(v.x), f2bf(v.y), f2bf(v.z), f2bf(v.w)};
        *(ushort4*)(dst + idx) = o;
        return;
    }
    const int row = b - 4096;         // 0..287
    const float* src; int Kh, i; unsigned short* dl;
    if (row < 64)       { src = w1; Kh = 64;  i = row;       dl = lw16 + (size_t)row * 1024; }
    else if (row < 128) { src = a1; Kh = 64;  i = row - 64;  dl = lw16 + (size_t)row * 1024; }
    else if (row < 160) { src = v1; Kh = 32;  i = row - 128; dl = lw16 + (size_t)(row - 128 + 128) * 1024; }
    else                { src = g1; Kh = 128; i = row - 160; dl = lw16 + (size_t)(row - 160 + 192) * 1024; }
    const int c0 = threadIdx.x * 4;
#pragma unroll
    for (int u = 0; u < 4; ++u)
        dl[c0 + u] = f2bf(src[(size_t)(c0 + u) * Kh + i]);
}

// ---------------------------------------------------------------------------
// Token-shift mix -> bf16 A-matrices for r/k/v projections and w/a/g LoRA.
// ---------------------------------------------------------------------------
__global__ __launch_bounds__(256) void xcvt(
    const float* __restrict__ x, const float* __restrict__ xprev,
    const float* __restrict__ x_r, const float* __restrict__ x_k,
    const float* __restrict__ x_v, const float* __restrict__ x_w,
    const float* __restrict__ x_a, const float* __restrict__ x_g,
    unsigned short* __restrict__ xr16, unsigned short* __restrict__ xk16,
    unsigned short* __restrict__ xv16, unsigned short* __restrict__ xw16,
    unsigned short* __restrict__ xa16, unsigned short* __restrict__ xg16)
{
    const int t = blockIdx.x;
    const int c0 = threadIdx.x * 4;
    const size_t base = (size_t)t * C_DIM + c0;
    float4 xv = *(const float4*)(x + base);
    float4 pv = (t == 0) ? *(const float4*)(xprev + c0)
                         : *(const float4*)(x + base - C_DIM);
    float4 dx = {pv.x - xv.x, pv.y - xv.y, pv.z - xv.z, pv.w - xv.w};
#define MIXOUT(mixp, dstp)                                                    \
    {                                                                          \
        float4 mv = *(const float4*)(mixp + c0);                               \
        ushort4 o = {f2bf(xv.x + dx.x * mv.x), f2bf(xv.y + dx.y * mv.y),       \
                     f2bf(xv.z + dx.z * mv.z), f2bf(xv.w + dx.w * mv.w)};      \
        *(ushort4*)(dstp + base) = o;                                          \
    }
    MIXOUT(x_r, xr16) MIXOUT(x_k, xk16) MIXOUT(x_v, xv16)
    MIXOUT(x_w, xw16) MIXOUT(x_a, xa16) MIXOUT(x_g, xg16)
#undef MIXOUT
}

// ---------------------------------------------------------------------------
// bf16 MFMA NT GEMM core: out[t,i] = sum_c A[t,c]*W[i,c], fp32 accumulate.
// ---------------------------------------------------------------------------
static __device__ __forceinline__ void gemm_core(
    const unsigned short* __restrict__ A, const unsigned short* __restrict__ W,
    float* __restrict__ out)
{
    __shared__ unsigned short Ab[2][128 * 32];
    __shared__ unsigned short Bb[2][64 * 32];
    const int tid = threadIdx.x;
    const int lane = tid & 63;
    const int w = tid >> 6;
    const int n0 = blockIdx.x * 64;
    const int t0 = blockIdx.y * 128;
    const int wm = (w & 1) * 64;
    const int wn = (w >> 1) * 32;
    const int srow = lane >> 2;
    const int scol = (lane & 3) * 8;

    f4_t acc[4][2];
#pragma unroll
    for (int i = 0; i < 4; ++i)
#pragma unroll
        for (int j = 0; j < 2; ++j)
            acc[i][j] = (f4_t){0.f, 0.f, 0.f, 0.f};

#pragma unroll
    for (int s = 0; s < 2; ++s) {
        const int i = 2 * w + s;
        __builtin_amdgcn_global_load_lds(
            (const AS1 unsigned int*)(A + (size_t)(t0 + i * 16 + srow) * 1024 + scol),
            (AS3 unsigned int*)(&Ab[0][i * 512 + lane * 8]), 16, 0, 0);
    }
    __builtin_amdgcn_global_load_lds(
        (const AS1 unsigned int*)(W + (size_t)(n0 + w * 16 + srow) * 1024 + scol),
        (AS3 unsigned int*)(&Bb[0][w * 512 + lane * 8]), 16, 0, 0);

    const int mrow = lane & 15;
    const int kq = (lane >> 4) * 8;
    for (int k0 = 0; k0 < 1024; k0 += 32) {
        const int cur = (k0 >> 5) & 1, nxt = cur ^ 1;
        __syncthreads();
        if (k0 + 32 < 1024) {
            const int k1 = k0 + 32;
#pragma unroll
            for (int s = 0; s < 2; ++s) {
                const int i = 2 * w + s;
                __builtin_amdgcn_global_load_lds(
                    (const AS1 unsigned int*)(A + (size_t)(t0 + i * 16 + srow) * 1024 + k1 + scol),
                    (AS3 unsigned int*)(&Ab[nxt][i * 512 + lane * 8]), 16, 0, 0);
            }
            __builtin_amdgcn_global_load_lds(
                (const AS1 unsigned int*)(W + (size_t)(n0 + w * 16 + srow) * 1024 + k1 + scol),
                (AS3 unsigned int*)(&Bb[nxt][w * 512 + lane * 8]), 16, 0, 0);
        }
        bf8_t af[4], bfr[2];
#pragma unroll
        for (int i = 0; i < 4; ++i)
            af[i] = *(const bf8_t*)(&Ab[cur][(wm + 16 * i + mrow) * 32 + kq]);
#pragma unroll
        for (int j = 0; j < 2; ++j)
            bfr[j] = *(const bf8_t*)(&Bb[cur][(wn + 16 * j + mrow) * 32 + kq]);
#pragma unroll
        for (int i = 0; i < 4; ++i)
#pragma unroll
            for (int j = 0; j < 2; ++j)
                acc[i][j] = __builtin_amdgcn_mfma_f32_16x16x32_bf16(
                    af[i], bfr[j], acc[i][j], 0, 0, 0);
    }
    const int crow = (lane >> 4) * 4;
    const int ccol = lane & 15;
#pragma unroll
    for (int i = 0; i < 4; ++i)
#pragma unroll
        for (int j = 0; j < 2; ++j)
#pragma unroll
            for (int u = 0; u < 4; ++u)
                out[(size_t)(t0 + wm + 16 * i + crow + u) * 1024
                    + n0 + wn + 16 * j + ccol] = acc[i][j][u];
}

__global__ __launch_bounds__(256) void gemm_bf16_3(
    const unsigned short* __restrict__ xr, const unsigned short* __restrict__ xk,
    const unsigned short* __restrict__ xv,
    const unsigned short* __restrict__ Wr, const unsigned short* __restrict__ Wk,
    const unsigned short* __restrict__ Wv,
    float* __restrict__ rB, float* __restrict__ kB, float* __restrict__ vB)
{
    const int z = blockIdx.z;
    const unsigned short* A = z == 0 ? xr : z == 1 ? xk : xv;
    const unsigned short* W = z == 0 ? Wr : z == 1 ? Wk : Wv;
    float* out = z == 0 ? rB : z == 1 ? kB : vB;
    gemm_core(A, W, out);
}

__global__ __launch_bounds__(256) void gemm_bf16(
    const unsigned short* __restrict__ A, const unsigned short* __restrict__ W,
    float* __restrict__ out)
{
    gemm_core(A, W, out);
}

// ---------------------------------------------------------------------------
// Fused LoRA stage-1 via MFMA: z = 0:w(tanh,N=64) 1:a(N=64) 2:v(N=32) 3:g(sig,N=128)
// ---------------------------------------------------------------------------
__global__ __launch_bounds__(256) void lora1m(
    const unsigned short* __restrict__ xw, const unsigned short* __restrict__ xa,
    const unsigned short* __restrict__ xv, const unsigned short* __restrict__ xg,
    const unsigned short* __restrict__ lw16,
    float* __restrict__ hw, float* __restrict__ ha, float* __restrict__ hv,
    float* __restrict__ hg)
{
    const int z = blockIdx.z;
    const unsigned short* A = z == 0 ? xw : z == 1 ? xa : z == 2 ? xv : xg;
    const unsigned short* W = lw16 + (size_t)(z == 0 ? 0 : z == 1 ? 64 : z == 2 ? 128 : 192) * 1024;
    float* out = z == 0 ? hw : z == 1 ? ha : z == 2 ? hv : hg;
    const int N  = z == 3 ? 128 : z == 2 ? 32 : 64;
    const int Ns = z == 3 ? 128 : 64;
    const int n0 = blockIdx.x * 64;
    if (n0 >= Ns) return;

    __shared__ unsigned short Ab[2][128 * 32];
    __shared__ unsigned short Bb[2][64 * 32];
    const int tid = threadIdx.x;
    const int lane = tid & 63;
    const int w = tid >> 6;
    const int t0 = blockIdx.y * 128;
    const int wm = (w & 1) * 64;
    const int wn = (w >> 1) * 32;
    const int srow = lane >> 2;
    const int scol = (lane & 3) * 8;

    f4_t acc[4][2];
#pragma unroll
    for (int i = 0; i < 4; ++i)
#pragma unroll
        for (int j = 0; j < 2; ++j)
            acc[i][j] = (f4_t){0.f, 0.f, 0.f, 0.f};

#pragma unroll
    for (int s = 0; s < 2; ++s) {
        const int i = 2 * w + s;
        __builtin_amdgcn_global_load_lds(
            (const AS1 unsigned int*)(A + (size_t)(t0 + i * 16 + srow) * 1024 + scol),
            (AS3 unsigned int*)(&Ab[0][i * 512 + lane * 8]), 16, 0, 0);
    }
    __builtin_amdgcn_global_load_lds(
        (const AS1 unsigned int*)(W + (size_t)(n0 + w * 16 + srow) * 1024 + scol),
        (AS3 unsigned int*)(&Bb[0][w * 512 + lane * 8]), 16, 0, 0);

    const int mrow = lane & 15;
    const int kq = (lane >> 4) * 8;
    for (int k0 = 0; k0 < 1024; k0 += 32) {
        const int cur = (k0 >> 5) & 1, nxt = cur ^ 1;
        __syncthreads();
        if (k0 + 32 < 1024) {
            const int k1 = k0 + 32;
#pragma unroll
            for (int s = 0; s < 2; ++s) {
                const int i = 2 * w + s;
                __builtin_amdgcn_global_load_lds(
                    (const AS1 unsigned int*)(A + (size_t)(t0 + i * 16 + srow) * 1024 + k1 + scol),
                    (AS3 unsigned int*)(&Ab[nxt][i * 512 + lane * 8]), 16, 0, 0);
            }
            __builtin_amdgcn_global_load_lds(
                (const AS1 unsigned int*)(W + (size_t)(n0 + w * 16 + srow) * 1024 + k1 + scol),
                (AS3 unsigned int*)(&Bb[nxt][w * 512 + lane * 8]), 16, 0, 0);
        }
        bf8_t af[4], bfr[2];
#pragma unroll
        for (int i = 0; i < 4; ++i)
            af[i] = *(const bf8_t*)(&Ab[cur][(wm + 16 * i + mrow) * 32 + kq]);
#pragma unroll
        for (int j = 0; j < 2; ++j)
            bfr[j] = *(const bf8_t*)(&Bb[cur][(wn + 16 * j + mrow) * 32 + kq]);
#pragma unroll
        for (int i = 0; i < 4; ++i)
#pragma unroll
            for (int j = 0; j < 2; ++j)
                acc[i][j] = __builtin_amdgcn_mfma_f32_16x16x32_bf16(
                    af[i], bfr[j], acc[i][j], 0, 0, 0);
    }
    const int crow = (lane >> 4) * 4;
    const int ccol = lane & 15;
#pragma unroll
    for (int i = 0; i < 4; ++i)
#pragma unroll
        for (int j = 0; j < 2; ++j) {
            const int col = n0 + wn + 16 * j + ccol;
            if (col < N) {
#pragma unroll
                for (int u = 0; u < 4; ++u) {
                    float vv = acc[i][j][u];
                    if (z == 0) vv = tanhf(vv);
                    else if (z == 3) vv = sigf(vv);
                    out[(size_t)(t0 + wm + 16 * i + crow + u) * N + col] = vv;
                }
            }
        }
}

// ---------------------------------------------------------------------------
// Fused LoRA-2 (w/a/v/g) + k post-process + PAIR-COMPOSED packet packing.
// r11: h-tile reads moved OFF the scalar pipe. r9/r10 showed dur invariant
// (57us) to TOK/occupancy/L2-traffic changes; the invariant quantity is the
// total s_load volume (block-uniform h reads -> compiler scalarizes; every
// load misses K$ since h is freshly written; SMEM pipe has shallow
// outstanding-miss capacity -> ~24us/CU serialized floor). Fix: add an
// opaque per-lane zero (mbcnt(~0,0)>>6 == 0) to the h addresses so the
// compiler cannot prove uniformity -> emits global_load_dwordx4 (VMEM,
// deep queues, latency hidden by 8 waves/SIMD). Arithmetic unchanged.
// Packet layout (768 floats) unchanged from r4.
// ---------------------------------------------------------------------------
#define TOK 4
__global__ __launch_bounds__(256) void lora2f(
    const float* __restrict__ hwB, const float* __restrict__ haB,
    const float* __restrict__ hvB, const float* __restrict__ hgB,
    const float* __restrict__ w2, const float* __restrict__ a2,
    const float* __restrict__ v2, const float* __restrict__ g2,
    const float* __restrict__ w0, const float* __restrict__ a0,
    const float* __restrict__ v0,
    const float* __restrict__ k_k, const float* __restrict__ k_a,
    const float* __restrict__ v_first, const float* __restrict__ rB,
    float* __restrict__ kB, float* __restrict__ vB, float* __restrict__ gB,
    float* __restrict__ pk)
{
    const int tid = threadIdx.x;
    const int t0 = blockIdx.y * TOK;
    const int i  = blockIdx.x * 256 + tid;
    const int h  = i >> 6;
    const int j  = i & 63;
    // Opaque zero: mbcnt_lo(~0,0) = lane index (<=63) for lo lanes, 32 for
    // hi lanes; >>6 == 0 always. Compiler can't fold -> h loads stay VMEM.
    const int zoff = (int)(__builtin_amdgcn_mbcnt_lo(~0u, 0u) >> 6);

    float av[TOK], ew[TOK], vf[TOK];
    { // a = sigmoid(a0 + ha@a2)
        float acc[TOK];
        const float b0 = a0[i];
#pragma unroll
        for (int tt = 0; tt < TOK; ++tt) acc[tt] = b0;
        for (int jj = 0; jj < 64; jj += 4) {
            const float q0 = a2[(size_t)(jj + 0) * C_DIM + i];
            const float q1 = a2[(size_t)(jj + 1) * C_DIM + i];
            const float q2 = a2[(size_t)(jj + 2) * C_DIM + i];
            const float q3 = a2[(size_t)(jj + 3) * C_DIM + i];
#pragma unroll
            for (int tt = 0; tt < TOK; ++tt) {
                float4 h4 = *(const float4*)(haB + zoff + (size_t)(t0 + tt) * 64 + jj);
                acc[tt] = fmaf(h4.x, q0, acc[tt]);
                acc[tt] = fmaf(h4.y, q1, acc[tt]);
                acc[tt] = fmaf(h4.z, q2, acc[tt]);
                acc[tt] = fmaf(h4.w, q3, acc[tt]);
            }
        }
#pragma unroll
        for (int tt = 0; tt < TOK; ++tt) av[tt] = sigf(acc[tt]);
    }
    { // exp(w)
        float acc[TOK];
        const float b0 = w0[i];
#pragma unroll
        for (int tt = 0; tt < TOK; ++tt) acc[tt] = b0;
        for (int jj = 0; jj < 64; jj += 4) {
            const float q0 = w2[(size_t)(jj + 0) * C_DIM + i];
            const float q1 = w2[(size_t)(jj + 1) * C_DIM + i];
            const float q2 = w2[(size_t)(jj + 2) * C_DIM + i];
            const float q3 = w2[(size_t)(jj + 3) * C_DIM + i];
#pragma unroll
            for (int tt = 0; tt < TOK; ++tt) {
                float4 h4 = *(const float4*)(hwB + zoff + (size_t)(t0 + tt) * 64 + jj);
                acc[tt] = fmaf(h4.x, q0, acc[tt]);
                acc[tt] = fmaf(h4.y, q1, acc[tt]);
                acc[tt] = fmaf(h4.z, q2, acc[tt]);
                acc[tt] = fmaf(h4.w, q3, acc[tt]);
            }
        }
#pragma unroll
        for (int tt = 0; tt < TOK; ++tt)
            ew[tt] = __expf(-0.6065306597126334f * sigf(acc[tt]));
    }
    { // v mix
        float acc[TOK];
        const float b0 = v0[i];
#pragma unroll
        for (int tt = 0; tt < TOK; ++tt) acc[tt] = b0;
        for (int jj = 0; jj < 32; jj += 4) {
            const float q0 = v2[(size_t)(jj + 0) * C_DIM + i];
            const float q1 = v2[(size_t)(jj + 1) * C_DIM + i];
            const float q2 = v2[(size_t)(jj + 2) * C_DIM + i];
            const float q3 = v2[(size_t)(jj + 3) * C_DIM + i];
#pragma unroll
            for (int tt = 0; tt < TOK; ++tt) {
                float4 h4 = *(const float4*)(hvB + zoff + (size_t)(t0 + tt) * 32 + jj);
                acc[tt] = fmaf(h4.x, q0, acc[tt]);
                acc[tt] = fmaf(h4.y, q1, acc[tt]);
                acc[tt] = fmaf(h4.z, q2, acc[tt]);
                acc[tt] = fmaf(h4.w, q3, acc[tt]);
            }
        }
#pragma unroll
        for (int tt = 0; tt < TOK; ++tt) {
            const size_t gi = (size_t)(t0 + tt) * C_DIM + i;
            const float s = sigf(acc[tt]);
            const float vr = vB[gi];
            vf[tt] = vr + (v_first[gi] - vr) * s;
            vB[gi] = vf[tt];
        }
    }
    { // g
        float acc[TOK];
#pragma unroll
        for (int tt = 0; tt < TOK; ++tt) acc[tt] = 0.f;
        for (int jj = 0; jj < 128; jj += 4) {
            const float q0 = g2[(size_t)(jj + 0) * C_DIM + i];
            const float q1 = g2[(size_t)(jj + 1) * C_DIM + i];
            const float q2 = g2[(size_t)(jj + 2) * C_DIM + i];
            const float q3 = g2[(size_t)(jj + 3) * C_DIM + i];
#pragma unroll
            for (int tt = 0; tt < TOK; ++tt) {
                float4 h4 = *(const float4*)(hgB + zoff + (size_t)(t0 + tt) * 128 + jj);
                acc[tt] = fmaf(h4.x, q0, acc[tt]);
                acc[tt] = fmaf(h4.y, q1, acc[tt]);
                acc[tt] = fmaf(h4.z, q2, acc[tt]);
                acc[tt] = fmaf(h4.w, q3, acc[tt]);
            }
        }
#pragma unroll
        for (int tt = 0; tt < TOK; ++tt)
            gB[(size_t)(t0 + tt) * C_DIM + i] = acc[tt];
    }
    // k post-process + pair-composed packing
    const float kkw = k_k[i], kaw = k_a[i];
    const size_t pbase = (size_t)h * 1024 * PAIR_F;
    for (int pt = 0; pt < TOK / 2; ++pt) {
        float r_[2], e_[2], kf_[2], v_[2], aa_[2], bb_[2];
#pragma unroll
        for (int u = 0; u < 2; ++u) {
            const int tt = 2 * pt + u;
            const size_t gi = (size_t)(t0 + tt) * C_DIM + i;
            const float kraw = kB[gi];
            const float kn = kraw * kkw;
            const float ss = red64(kn * kn);
            const float sc = 1.f / fmaxf(sqrtf(ss), 1e-12f);
            const float kk = kn * sc;
            const float a_ = av[tt];
            const float kf = kraw * (1.f + (a_ - 1.f) * kaw);
            kB[gi] = kf;
            r_[u] = rB[gi];
            e_[u] = ew[tt];
            kf_[u] = kf;
            v_[u] = vf[tt];
            aa_[u] = -kk;
            bb_[u] = kk * a_;
        }
        const float E   = e_[0] * e_[1];
        const float A2e = e_[0] * aa_[1];
        const float B1e = bb_[0] * e_[1];
        const float K1e = kf_[0] * e_[1];
        const float R1e = e_[0] * r_[0];
        const float cba = red64(bb_[0] * aa_[1]);
        const float cka = red64(kf_[0] * aa_[1]);
        const float cbr = red64(bb_[0] * r_[0]);
        const float ckr = red64(kf_[0] * r_[0]);
        const float cbr2  = red64(B1e * r_[1]);
        const float ckr2  = red64(K1e * r_[1]);
        const float cb2r2 = red64(bb_[1] * r_[1]);
        const float ck2r2 = red64(kf_[1] * r_[1]);
        float* p = pk + pbase + (size_t)(blockIdx.y * (TOK / 2) + pt) * PAIR_F;
        p[j]        = E;
        p[64 + j]   = aa_[0];
        p[128 + j]  = A2e;
        p[192 + j]  = B1e;
        p[256 + j]  = K1e;
        p[320 + j]  = bb_[1];
        p[384 + j]  = kf_[1];
        p[448 + j]  = R1e;
        p[512 + j]  = E * r_[1];          // R2e = E ⊙ R2
        p[576 + 2 * j]     = v_[0];       // vv interleaved
        p[576 + 2 * j + 1] = v_[1];
        if (j == 0) {
            p[704] = cba;  p[705] = cka;  p[706] = cbr;  p[707] = ckr;
            p[708] = cbr2; p[709] = ckr2; p[710] = cb2r2; p[711] = ck2r2;
        }
    }
}

// ---------------------------------------------------------------------------
// CHUNKED SCAN (r9 structure, unchanged): NCH=32/CPAIR=32, 2048 waves per
// scan phase (2 waves/SIMD); Pbuf aliases y region; CSbuf in-place combine.
// ---------------------------------------------------------------------------
struct SlotPC {
    float4 E, A1, A2e, B1e, K1e, B2, K2;
    float4 vva, vvb;   // {v1,v2} for rows rbase..rbase+3
    float4 sc;         // cba, cka, cbr, ckr (only x,y used here)
};

static __device__ __forceinline__ void slot_load_pc(
    SlotPC& K, const float* __restrict__ p, int j0, int rb2)
{
    K.E   = *(const float4*)(p + j0);
    K.A1  = *(const float4*)(p + 64 + j0);
    K.A2e = *(const float4*)(p + 128 + j0);
    K.B1e = *(const float4*)(p + 192 + j0);
    K.K1e = *(const float4*)(p + 256 + j0);
    K.B2  = *(const float4*)(p + 320 + j0);
    K.K2  = *(const float4*)(p + 384 + j0);
    K.vva = *(const float4*)(p + 576 + rb2);
    K.vvb = *(const float4*)(p + 576 + rb2 + 4);
    K.sc  = *(const float4*)(p + 704);
}

static __device__ __forceinline__ void pair_pc(
    f2_t* PSl, f2_t* PSh, f2_t* CSl, f2_t* CSh, const SlotPC& K)
{
    float pu1[4], pu2[4], cu1[4], cu2[4];
#pragma unroll
    for (int r = 0; r < 4; ++r) {
        pu1[r] = red16(dot4pk(PSl[r], PSh[r], K.A1));
        pu2[r] = red16(dot4pk(PSl[r], PSh[r], K.A2e));
        cu1[r] = red16(dot4pk(CSl[r], CSh[r], K.A1));
        cu2[r] = red16(dot4pk(CSl[r], CSh[r], K.A2e));
    }
#pragma unroll
    for (int r = 0; r < 4; ++r) {
        { // P update: v-terms exactly zero -> dropped (bitwise identical)
            const float sa1 = pu1[r];
            const float sa2 = fmaf(sa1, K.sc.x, pu2[r]);
            const f2_t sa1v = f2bc(sa1), sa2v = f2bc(sa2);
            f2_t nl = PSl[r] * lo2(K.E), nh = PSh[r] * hi2(K.E);
            nl = fma2(sa1v, lo2(K.B1e), nl); nh = fma2(sa1v, hi2(K.B1e), nh);
            nl = fma2(sa2v, lo2(K.B2), nl);  nh = fma2(sa2v, hi2(K.B2), nh);
            PSl[r] = nl; PSh[r] = nh;
        }
        { // C update: full recurrence from zero init
            const float v1 = r == 0 ? K.vva.x : r == 1 ? K.vva.z
                           : r == 2 ? K.vvb.x : K.vvb.z;
            const float v2 = r == 0 ? K.vva.y : r == 1 ? K.vva.w
                           : r == 2 ? K.vvb.y : K.vvb.w;
            const float sa1 = cu1[r];
            const float sa2 = fmaf(v1, K.sc.y, fmaf(sa1, K.sc.x, cu2[r]));
            const f2_t sa1v = f2bc(sa1), sa2v = f2bc(sa2);
            const f2_t v1v = f2bc(v1), v2v = f2bc(v2);
            f2_t nl = CSl[r] * lo2(K.E), nh = CSh[r] * hi2(K.E);
            nl = fma2(sa1v, lo2(K.B1e), nl); nh = fma2(sa1v, hi2(K.B1e), nh);
            nl = fma2(v1v, lo2(K.K1e), nl);  nh = fma2(v1v, hi2(K.K1e), nh);
            nl = fma2(sa2v, lo2(K.B2), nl);  nh = fma2(sa2v, hi2(K.B2), nh);
            nl = fma2(v2v, lo2(K.K2), nl);   nh = fma2(v2v, hi2(K.K2), nh);
            CSl[r] = nl; CSh[r] = nh;
        }
    }
}

// grid: b = h + 16*w + 64*c  (w stride 16 => same (h,c) on same XCD mod 8)
__global__ __launch_bounds__(64, 1) void pc_fused(
    const float* __restrict__ pk, float* __restrict__ Pbuf,
    float* __restrict__ Cbuf)
{
    const int b = blockIdx.x;
    const int h = b & 15;
    const int w = (b >> 4) & 3;
    const int c = b >> 6;
    const int l = threadIdx.x;
    const int q = l >> 4;
    const int j0 = (l & 15) * 4;
    const int rbase = w * 16 + q * 4;
    const int rb2 = 2 * rbase;
    const float* hbase = pk + ((size_t)h * 1024 + (size_t)c * CPAIR) * PAIR_F;

    f2_t PSl[4], PSh[4], CSl[4], CSh[4];
#pragma unroll
    for (int r = 0; r < 4; ++r) {
        const int row = rbase + r;
        PSl[r] = (f2_t){j0 == row ? 1.f : 0.f, j0 + 1 == row ? 1.f : 0.f};
        PSh[r] = (f2_t){j0 + 2 == row ? 1.f : 0.f, j0 + 3 == row ? 1.f : 0.f};
        CSl[r] = (f2_t){0.f, 0.f};
        CSh[r] = (f2_t){0.f, 0.f};
    }

    SlotPC s0, s1, s2, s3;
    slot_load_pc(s0, hbase + 0 * PAIR_F, j0, rb2);
    slot_load_pc(s1, hbase + 1 * PAIR_F, j0, rb2);
    slot_load_pc(s2, hbase + 2 * PAIR_F, j0, rb2);
    slot_load_pc(s3, hbase + 3 * PAIR_F, j0, rb2);
    __builtin_amdgcn_sched_barrier(0);

    for (int i = 0; i < CPAIR - 4; i += 4) {
        const float* pl = hbase + (size_t)(i + 4) * PAIR_F;
        // Pinned ring: loads for pair i+4 issue right after compute of pair i
        // and may NOT sink into later computes.
        pair_pc(PSl, PSh, CSl, CSh, s0); slot_load_pc(s0, pl + 0 * PAIR_F, j0, rb2);
        __builtin_amdgcn_sched_barrier(0);
        pair_pc(PSl, PSh, CSl, CSh, s1); slot_load_pc(s1, pl + 1 * PAIR_F, j0, rb2);
        __builtin_amdgcn_sched_barrier(0);
        pair_pc(PSl, PSh, CSl, CSh, s2); slot_load_pc(s2, pl + 2 * PAIR_F, j0, rb2);
        __builtin_amdgcn_sched_barrier(0);
        pair_pc(PSl, PSh, CSl, CSh, s3); slot_load_pc(s3, pl + 3 * PAIR_F, j0, rb2);
        __builtin_amdgcn_sched_barrier(0);
    }
    pair_pc(PSl, PSh, CSl, CSh, s0);
    pair_pc(PSl, PSh, CSl, CSh, s1);
    pair_pc(PSl, PSh, CSl, CSh, s2);
    pair_pc(PSl, PSh, CSl, CSh, s3);

    const size_t cb64 = ((size_t)h * NCH + c) * 4096;
#pragma unroll
    for (int r = 0; r < 4; ++r) {
        *(float4*)(Pbuf + cb64 + (size_t)(rbase + r) * 64 + j0) =
            (float4){PSl[r].x, PSl[r].y, PSh[r].x, PSh[r].y};
        *(float4*)(Cbuf + cb64 + (size_t)(rbase + r) * 64 + j0) =
            (float4){CSl[r].x, CSl[r].y, CSh[r].x, CSh[r].y};
    }
}

// Phase 2: serial chunk combine S <- S*P_c + C_c. IN-PLACE Scbuf: each
// thread loads its C_c value, then overwrites the slot with the chunk's
// START state (same address, same thread -> no race). 256 blocks x 64 thr.
__global__ __launch_bounds__(64) void combine(
    const float* __restrict__ Pbuf, float* __restrict__ CSbuf,
    const float* __restrict__ init_state)
{
    const int b = blockIdx.x;
    const int h = b & 15;
    const int g = b >> 4;
    const int l = threadIdx.x;
    const int vl = l >> 4;
    const int vidx = g * 4 + vl;
    const int j0 = (l & 15) * 4;
    __shared__ __align__(16) float Pl[64 * 64];
    __shared__ __align__(16) float sl[4 * 64];

    float4 s = *(const float4*)(init_state + h * 4096 + vidx * 64 + j0);
    for (int c = 0; c < NCH; ++c) {
        const size_t cbase = ((size_t)h * NCH + c) * 4096;
        float* cp = CSbuf + cbase + (size_t)vidx * 64 + j0;
        float4 Cv = *(const float4*)cp;   // load C_c FIRST
        *(float4*)cp = s;                 // then store chunk-start state
        const float* Psrc = Pbuf + cbase;
#pragma unroll
        for (int t = 0; t < 16; ++t)
            *(float4*)(&Pl[t * 256 + l * 4]) = *(const float4*)(Psrc + t * 256 + l * 4);
        *(float4*)(&sl[vl * 64 + j0]) = s;
        __syncthreads();
        f2_t al = {Cv.x, Cv.y}, ah = {Cv.z, Cv.w};
        for (int k = 0; k < 64; ++k) {
            const float sk = sl[vl * 64 + k];
            float4 Pr = *(const float4*)(&Pl[k * 64 + j0]);
            al = fma2(f2bc(sk), lo2(Pr), al);
            ah = fma2(f2bc(sk), hi2(Pr), ah);
        }
        s = (float4){al.x, al.y, ah.x, ah.y};
        __syncthreads();
    }
}

// ---- output scan: 4 rows/lane-group, 2-slot pinned ring -------------------
struct SlotO {
    float4 E, A1, A2e, B1e, K1e, B2, K2, R1e, R2e;
    float4 vva, vvb;
    float4 sc, sc2;
};

static __device__ __forceinline__ void slot_load_o(
    SlotO& K, const float* __restrict__ p, int j0, int rb2)
{
    K.E   = *(const float4*)(p + j0);
    K.A1  = *(const float4*)(p + 64 + j0);
    K.A2e = *(const float4*)(p + 128 + j0);
    K.B1e = *(const float4*)(p + 192 + j0);
    K.K1e = *(const float4*)(p + 256 + j0);
    K.B2  = *(const float4*)(p + 320 + j0);
    K.K2  = *(const float4*)(p + 384 + j0);
    K.R1e = *(const float4*)(p + 448 + j0);
    K.R2e = *(const float4*)(p + 512 + j0);
    K.vva = *(const float4*)(p + 576 + rb2);
    K.vvb = *(const float4*)(p + 576 + rb2 + 4);
    K.sc  = *(const float4*)(p + 704);
    K.sc2 = *(const float4*)(p + 708);
}

static __device__ __forceinline__ void pair_out(
    f2_t* Sl, f2_t* Sh, const SlotO& K, float4& o1v, float4& o2v)
{
    float u1[4], u2[4], op[4], oz[4];
#pragma unroll
    for (int r = 0; r < 4; ++r) {
        u1[r] = red16(dot4pk(Sl[r], Sh[r], K.A1));
        u2[r] = red16(dot4pk(Sl[r], Sh[r], K.A2e));
        op[r] = red16(dot4pk(Sl[r], Sh[r], K.R1e));
        oz[r] = red16(dot4pk(Sl[r], Sh[r], K.R2e));
    }
    float o1a[4], o2a[4];
#pragma unroll
    for (int r = 0; r < 4; ++r) {
        const float v1 = r == 0 ? K.vva.x : r == 1 ? K.vva.z
                       : r == 2 ? K.vvb.x : K.vvb.z;
        const float v2 = r == 0 ? K.vva.y : r == 1 ? K.vva.w
                       : r == 2 ? K.vvb.y : K.vvb.w;
        const float sa1 = u1[r];
        const float sa2 = fmaf(v1, K.sc.y, fmaf(sa1, K.sc.x, u2[r]));
        o1a[r] = fmaf(v1, K.sc.w, fmaf(sa1, K.sc.z, op[r]));
        o2a[r] = fmaf(v2, K.sc2.w, fmaf(sa2, K.sc2.z,
                 fmaf(v1, K.sc2.y, fmaf(sa1, K.sc2.x, oz[r]))));
        const f2_t sa1v = f2bc(sa1), sa2v = f2bc(sa2);
        const f2_t v1v = f2bc(v1), v2v = f2bc(v2);
        f2_t nl = Sl[r] * lo2(K.E), nh = Sh[r] * hi2(K.E);
        nl = fma2(sa1v, lo2(K.B1e), nl); nh = fma2(sa1v, hi2(K.B1e), nh);
        nl = fma2(v1v, lo2(K.K1e), nl);  nh = fma2(v1v, hi2(K.K1e), nh);
        nl = fma2(sa2v, lo2(K.B2), nl);  nh = fma2(sa2v, hi2(K.B2), nh);
        nl = fma2(v2v, lo2(K.K2), nl);   nh = fma2(v2v, hi2(K.K2), nh);
        Sl[r] = nl; Sh[r] = nh;
    }
    o1v = (float4){o1a[0], o1a[1], o1a[2], o1a[3]};
    o2v = (float4){o2a[0], o2a[1], o2a[2], o2a[3]};
}

__global__ __launch_bounds__(64, 1) void out_scan(
    const float* __restrict__ pk, const float* __restrict__ Scbuf,
    float* __restrict__ y)
{
    const int b = blockIdx.x;
    const int h = b & 15;
    const int w = (b >> 4) & 3;
    const int c = b >> 6;
    const int l = threadIdx.x;
    const int q = l >> 4;
    const int j0 = (l & 15) * 4;
    const int rbase = w * 16 + q * 4;
    const int rb2 = 2 * rbase;
    const int cb = h * 64;
    const float* hbase = pk + ((size_t)h * 1024 + (size_t)c * CPAIR) * PAIR_F;
    const size_t cb64 = ((size_t)h * NCH + c) * 4096;

    f2_t Sl[4], Sh[4];
#pragma unroll
    for (int r = 0; r < 4; ++r) {
        float4 S4 = *(const float4*)(Scbuf + cb64 + (size_t)(rbase + r) * 64 + j0);
        Sl[r] = (f2_t){S4.x, S4.y};
        Sh[r] = (f2_t){S4.z, S4.w};
    }

    SlotO s0, s1;
    slot_load_o(s0, hbase + 0 * PAIR_F, j0, rb2);
    slot_load_o(s1, hbase + 1 * PAIR_F, j0, rb2);
    __builtin_amdgcn_sched_barrier(0);

    const bool wr = (l & 15) == 0;
    const int pi0 = c * CPAIR;
    float4 o1v, o2v;
#define OUT_STORE(pidx)                                                       \
    if (wr) {                                                                 \
        float* yp = y + (size_t)(2 * (pidx)) * C_DIM + cb + rbase;            \
        *(float4*)yp = o1v;                                                   \
        *(float4*)(yp + C_DIM) = o2v;                                         \
    }
    for (int i = 0; i < CPAIR - 2; i += 2) {
        // 2-slot pinned ring: load for pair i+2 issues right after compute
        // of pair i; sched_barrier stops it sinking into pair i+1's compute.
        pair_out(Sl, Sh, s0, o1v, o2v);
        slot_load_o(s0, hbase + (size_t)(i + 2) * PAIR_F, j0, rb2);
        __builtin_amdgcn_sched_barrier(0);
        OUT_STORE(pi0 + i)
        pair_out(Sl, Sh, s1, o1v, o2v);
        if (i + 3 < CPAIR)
            slot_load_o(s1, hbase + (size_t)(i + 3) * PAIR_F, j0, rb2);
        __builtin_amdgcn_sched_barrier(0);
        OUT_STORE(pi0 + i + 1)
    }
    pair_out(Sl, Sh, s0, o1v, o2v);
    OUT_STORE(pi0 + CPAIR - 2)
    pair_out(Sl, Sh, s1, o1v, o2v);
    OUT_STORE(pi0 + CPAIR - 1)
#undef OUT_STORE
}

// ---------------------------------------------------------------------------
// GroupNorm + bonus + *g ; writes bf16 (xo*g) for the final MFMA GEMM.
// ---------------------------------------------------------------------------
__global__ __launch_bounds__(256) void gn_bonus(
    const float* __restrict__ y, const float* __restrict__ rb,
    const float* __restrict__ kb, const float* __restrict__ vb,
    const float* __restrict__ gb, const float* __restrict__ r_k,
    const float* __restrict__ lnw, const float* __restrict__ lnb,
    unsigned short* __restrict__ yg)
{
    const int t = blockIdx.x, tid = threadIdx.x;
    const int c0 = tid << 2;
    const size_t base = (size_t)t * C_DIM + c0;
    float4 yv = *(const float4*)(y + base);
    float sum = yv.x + yv.y + yv.z + yv.w;
    float ss  = yv.x * yv.x + yv.y * yv.y + yv.z * yv.z + yv.w * yv.w;
    float4 rv = *(const float4*)(rb + base);
    float4 kv = *(const float4*)(kb + base);
    float4 rkv = *(const float4*)(r_k + c0);
    float dot = rv.x * kv.x * rkv.x + rv.y * kv.y * rkv.y +
                rv.z * kv.z * rkv.z + rv.w * kv.w * rkv.w;
#pragma unroll
    for (int m = 1; m <= 8; m <<= 1) {
        sum += __shfl_xor(sum, m);
        ss  += __shfl_xor(ss, m);
        dot += __shfl_xor(dot, m);
    }
    const float mu = sum * 0.015625f;
    const float var = ss * 0.015625f - mu * mu;
    const float rstd = rsqrtf(var + 0.00064f);
    float4 wv = *(const float4*)(lnw + c0);
    float4 bv = *(const float4*)(lnb + c0);
    float4 vv = *(const float4*)(vb + base);
    float4 gv = *(const float4*)(gb + base);
    ushort4 o;
    o.x = f2bf(((yv.x - mu) * rstd * wv.x + bv.x + dot * vv.x) * gv.x);
    o.y = f2bf(((yv.y - mu) * rstd * wv.y + bv.y + dot * vv.y) * gv.y);
    o.z = f2bf(((yv.z - mu) * rstd * wv.z + bv.z + dot * vv.z) * gv.z);
    o.w = f2bf(((yv.w - mu) * rstd * wv.w + bv.w + dot * vv.w) * gv.w);
    *(ushort4*)(yg + base) = o;
}

// ---------------------------------------------------------------------------
extern "C" void kernel_launch(void* const* d_in, const int* in_sizes, int n_in,
                              void* d_out, int out_size, void* d_ws, size_t ws_size,
                              hipStream_t stream)
{
    (void)in_sizes; (void)n_in; (void)out_size; (void)ws_size;
    const float* x       = (const float*)d_in[0];
    const float* v_first = (const float*)d_in[1];
    const float* x_prev  = (const float*)d_in[2];
    const float* init_st = (const float*)d_in[3];
    const float* x_r = (const float*)d_in[4];
    const float* x_w = (const float*)d_in[5];
    const float* x_k = (const float*)d_in[6];
    const float* x_v = (const float*)d_in[7];
    const float* x_a = (const float*)d_in[8];
    const float* x_g = (const float*)d_in[9];
    const float* w0  = (const float*)d_in[10];
    const float* a0  = (const float*)d_in[11];
    const float* v0  = (const float*)d_in[12];
    const float* k_k = (const float*)d_in[13];
    const float* k_a = (const float*)d_in[14];
    const float* w1  = (const float*)d_in[15];
    const float* w2  = (const float*)d_in[16];
    const float* a1  = (const float*)d_in[17];
    const float* a2  = (const float*)d_in[18];
    const float* v1  = (const float*)d_in[19];
    const float* v2  = (const float*)d_in[20];
    const float* g1  = (const float*)d_in[21];
    const float* g2  = (const float*)d_in[22];
    const float* r_k = (const float*)d_in[23];
    const float* Wr  = (const float*)d_in[24];
    const float* Wk  = (const float*)d_in[25];
    const float* Wv  = (const float*)d_in[26];
    const float* Wo  = (const float*)d_in[27];
    const float* ln_w = (const float*)d_in[28];
    const float* ln_b = (const float*)d_in[29];

    float* out = (float*)d_out;
    float* ws  = (float*)d_ws;
    const size_t NE = (size_t)T_LEN * C_DIM;   // 2M
    const size_t WE = (size_t)C_DIM * C_DIM;   // 1M
    float* rB  = ws;
    float* kB  = ws + NE;
    float* vB  = ws + 2 * NE;
    float* gB  = ws + 3 * NE;
    float* hwB = ws + 4 * NE;                  // T*64
    float* haB = hwB + (size_t)T_LEN * 64;
    float* hvB = haB + (size_t)T_LEN * 64;
    float* hgB = hvB + (size_t)T_LEN * 32;     // h region < NE/2
    float* pk  = ws + 4 * NE + NE / 2;         // 6*NE floats (16*1024*768)
    unsigned short* b16 = (unsigned short*)(ws + 10 * NE + NE / 2);
    unsigned short* xr16 = b16;                // NE shorts
    unsigned short* xk16 = b16 + NE;
    unsigned short* xv16 = b16 + 2 * NE;
    unsigned short* Wr16 = b16 + 3 * NE;       // 4*WE shorts
    unsigned short* Wk16 = Wr16 + WE;
    unsigned short* Wv16 = Wr16 + 2 * WE;
    unsigned short* Wo16 = Wr16 + 3 * WE;
    unsigned short* yg16 = b16 + 3 * NE + 4 * WE;  // NE shorts
    unsigned short* lw16 = yg16 + NE;              // 320K shorts (LoRA weights)
    // xw/xa/xg bf16 live in the pk region (pk written later by lora2f)
    unsigned short* xw16 = (unsigned short*)pk;
    unsigned short* xa16 = xw16 + NE;
    unsigned short* xg16 = xw16 + 2 * NE;
    // yB aliases xr16+xk16 (consumed by gemms before the scan writes it)
    float* yB = (float*)xr16;
    // Chunk-scan buffers (NCH=32 -> 2M floats each):
    //   Pbuf  <- y region (xr16+xk16)
    //   CSbuf <- xv16+Wr16+Wk16 (2M floats exactly; dead after gemm3/lora1m)
    float* Pbuf  = (float*)xr16;   // 16h x 32c x 64 x 64 = 2M floats
    float* CSbuf = (float*)xv16;   // 2M floats (xv16..Wk16)

    wcvtall<<<4384, 256, 0, stream>>>(Wr, Wk, Wv, Wo, w1, a1, v1, g1,
                                      Wr16, lw16);
    xcvt<<<T_LEN, 256, 0, stream>>>(x, x_prev, x_r, x_k, x_v, x_w, x_a, x_g,
                                    xr16, xk16, xv16, xw16, xa16, xg16);

    gemm_bf16_3<<<dim3(16, 16, 3), 256, 0, stream>>>(
        xr16, xk16, xv16, Wr16, Wk16, Wv16, rB, kB, vB);

    lora1m<<<dim3(2, 16, 4), 256, 0, stream>>>(
        xw16, xa16, xv16, xg16, lw16, hwB, haB, hvB, hgB);

    lora2f<<<dim3(4, T_LEN / TOK), 256, 0, stream>>>(
        hwB, haB, hvB, hgB, w2, a2, v2, g2, w0, a0, v0,
        k_k, k_a, v_first, rB, kB, vB, gB, pk);

    pc_fused<<<16 * 4 * NCH, 64, 0, stream>>>(pk, Pbuf, CSbuf);
    combine<<<256, 64, 0, stream>>>(Pbuf, CSbuf, init_st);
    out_scan<<<16 * 4 * NCH, 64, 0, stream>>>(pk, CSbuf, yB);

    gn_bonus<<<T_LEN, 256, 0, stream>>>(yB, rB, kB, vB, gB, r_k, ln_w, ln_b, yg16);
    gemm_bf16<<<dim3(16, 16), 256, 0, stream>>>(yg16, Wo16, out);
}

// Round 12
// 369.446 us; speedup vs baseline: 1.1641x; 1.1641x over previous
//
#include <hip/hip_runtime.h>

#define T_LEN 2048
#define C_DIM 1024
#define PAIR_F 768          // floats per (head, step-pair) packet
#define NCH 32              // chunks
#define CPAIR 32            // pairs per chunk (NCH*CPAIR = 1024)

#define AS1 __attribute__((address_space(1)))
#define AS3 __attribute__((address_space(3)))

typedef __attribute__((ext_vector_type(8))) short bf8_t;
typedef __attribute__((ext_vector_type(4))) float f4_t;
typedef __attribute__((ext_vector_type(2))) float f2_t;

static __device__ __forceinline__ float sigf(float x) {
    return 1.f / (1.f + __expf(-x));
}
static __device__ __forceinline__ unsigned short f2bf(float f) {
    unsigned u = __float_as_uint(f);
    u += 0x7fff + ((u >> 16) & 1);
    return (unsigned short)(u >> 16);
}

// ---- cross-lane reduction helpers ----------------------------------------
static __device__ __forceinline__ float red16(float x) {
    int xi;
    xi = __builtin_amdgcn_mov_dpp(__float_as_int(x), 0x128, 0xf, 0xf, true);
    x += __int_as_float(xi);
    xi = __builtin_amdgcn_mov_dpp(__float_as_int(x), 0x124, 0xf, 0xf, true);
    x += __int_as_float(xi);
    xi = __builtin_amdgcn_mov_dpp(__float_as_int(x), 0x122, 0xf, 0xf, true);
    x += __int_as_float(xi);
    xi = __builtin_amdgcn_mov_dpp(__float_as_int(x), 0x121, 0xf, 0xf, true);
    x += __int_as_float(xi);
    return x;
}
// full 64-lane sum: DPP within 16 (VALU pipe), then only 2 DS-ops
static __device__ __forceinline__ float red64(float x) {
    x = red16(x);
    x += __shfl_xor(x, 16);
    x += __shfl_xor(x, 32);
    return x;
}

static __device__ __forceinline__ f2_t f2bc(float s) { return (f2_t){s, s}; }
static __device__ __forceinline__ f2_t fma2(f2_t a, f2_t b, f2_t c) {
    return __builtin_elementwise_fma(a, b, c);
}
static __device__ __forceinline__ f2_t lo2(const float4& v) { return (f2_t){v.x, v.y}; }
static __device__ __forceinline__ f2_t hi2(const float4& v) { return (f2_t){v.z, v.w}; }

static __device__ __forceinline__ float dot4pk(f2_t Sl, f2_t Sh, const float4& A) {
    f2_t m = Sl * lo2(A);
    m = fma2(Sh, hi2(A), m);
    return m.x + m.y;
}

// ---------------------------------------------------------------------------
// Convert the four 1024x1024 fp32 weights into one bf16 block (1M strides),
// the transposed LoRA stage-1 weights (blocks 4096..4383), and (r12) the
// transposed bf16 g2t[1024][128] (blocks 4384..4895) for the MFMA g-GEMM.
// ---------------------------------------------------------------------------
__global__ __launch_bounds__(256) void wcvtall(
    const float* __restrict__ Wr, const float* __restrict__ Wk,
    const float* __restrict__ Wv, const float* __restrict__ Wo,
    const float* __restrict__ w1, const float* __restrict__ a1,
    const float* __restrict__ v1, const float* __restrict__ g1,
    const float* __restrict__ g2,
    unsigned short* __restrict__ dst, unsigned short* __restrict__ lw16,
    unsigned short* __restrict__ g2t16)
{
    const int b = blockIdx.x;
    if (b < 4096) {
        const size_t idx = ((size_t)b * 256 + threadIdx.x) * 4;
        const int sel = (int)(idx >> 20);
        const float* src = sel == 0 ? Wr : sel == 1 ? Wk : sel == 2 ? Wv : Wo;
        float4 v = *(const float4*)(src + (idx & 0xFFFFF));
        ushort4 o = {f2bf(v.x), f2bf(v.y), f2bf(v.z), f2bf(v.w)};
        *(ushort4*)(dst + idx) = o;
        return;
    }
    if (b >= 4384) {                  // g2t: [1024][128] bf16, 2 rows/block
        const int rr = b - 4384;      // 0..511
        const int i  = rr * 2 + (threadIdx.x >> 7);
        const int c  = threadIdx.x & 127;
        g2t16[(size_t)i * 128 + c] = f2bf(g2[(size_t)c * C_DIM + i]);
        return;
    }
    const int row = b - 4096;         // 0..287
    const float* src; int Kh, i; unsigned short* dl;
    if (row < 64)       { src = w1; Kh = 64;  i = row;       dl = lw16 + (size_t)row * 1024; }
    else if (row < 128) { src = a1; Kh = 64;  i = row - 64;  dl = lw16 + (size_t)row * 1024; }
    else if (row < 160) { src = v1; Kh = 32;  i = row - 128; dl = lw16 + (size_t)(row - 128 + 128) * 1024; }
    else                { src = g1; Kh = 128; i = row - 160; dl = lw16 + (size_t)(row - 160 + 192) * 1024; }
    const int c0 = threadIdx.x * 4;
#pragma unroll
    for (int u = 0; u < 4; ++u)
        dl[c0 + u] = f2bf(src[(size_t)(c0 + u) * Kh + i]);
}

// ---------------------------------------------------------------------------
// Token-shift mix -> bf16 A-matrices for r/k/v projections and w/a/g LoRA.
// ---------------------------------------------------------------------------
__global__ __launch_bounds__(256) void xcvt(
    const float* __restrict__ x, const float* __restrict__ xprev,
    const float* __restrict__ x_r, const float* __restrict__ x_k,
    const float* __restrict__ x_v, const float* __restrict__ x_w,
    const float* __restrict__ x_a, const float* __restrict__ x_g,
    unsigned short* __restrict__ xr16, unsigned short* __restrict__ xk16,
    unsigned short* __restrict__ xv16, unsigned short* __restrict__ xw16,
    unsigned short* __restrict__ xa16, unsigned short* __restrict__ xg16)
{
    const int t = blockIdx.x;
    const int c0 = threadIdx.x * 4;
    const size_t base = (size_t)t * C_DIM + c0;
    float4 xv = *(const float4*)(x + base);
    float4 pv = (t == 0) ? *(const float4*)(xprev + c0)
                         : *(const float4*)(x + base - C_DIM);
    float4 dx = {pv.x - xv.x, pv.y - xv.y, pv.z - xv.z, pv.w - xv.w};
#define MIXOUT(mixp, dstp)                                                    \
    {                                                                          \
        float4 mv = *(const float4*)(mixp + c0);                               \
        ushort4 o = {f2bf(xv.x + dx.x * mv.x), f2bf(xv.y + dx.y * mv.y),       \
                     f2bf(xv.z + dx.z * mv.z), f2bf(xv.w + dx.w * mv.w)};      \
        *(ushort4*)(dstp + base) = o;                                          \
    }
    MIXOUT(x_r, xr16) MIXOUT(x_k, xk16) MIXOUT(x_v, xv16)
    MIXOUT(x_w, xw16) MIXOUT(x_a, xa16) MIXOUT(x_g, xg16)
#undef MIXOUT
}

// ---------------------------------------------------------------------------
// bf16 MFMA NT GEMM core: out[t,i] = sum_c A[t,c]*W[i,c], fp32 accumulate.
// ---------------------------------------------------------------------------
static __device__ __forceinline__ void gemm_core(
    const unsigned short* __restrict__ A, const unsigned short* __restrict__ W,
    float* __restrict__ out)
{
    __shared__ unsigned short Ab[2][128 * 32];
    __shared__ unsigned short Bb[2][64 * 32];
    const int tid = threadIdx.x;
    const int lane = tid & 63;
    const int w = tid >> 6;
    const int n0 = blockIdx.x * 64;
    const int t0 = blockIdx.y * 128;
    const int wm = (w & 1) * 64;
    const int wn = (w >> 1) * 32;
    const int srow = lane >> 2;
    const int scol = (lane & 3) * 8;

    f4_t acc[4][2];
#pragma unroll
    for (int i = 0; i < 4; ++i)
#pragma unroll
        for (int j = 0; j < 2; ++j)
            acc[i][j] = (f4_t){0.f, 0.f, 0.f, 0.f};

#pragma unroll
    for (int s = 0; s < 2; ++s) {
        const int i = 2 * w + s;
        __builtin_amdgcn_global_load_lds(
            (const AS1 unsigned int*)(A + (size_t)(t0 + i * 16 + srow) * 1024 + scol),
            (AS3 unsigned int*)(&Ab[0][i * 512 + lane * 8]), 16, 0, 0);
    }
    __builtin_amdgcn_global_load_lds(
        (const AS1 unsigned int*)(W + (size_t)(n0 + w * 16 + srow) * 1024 + scol),
        (AS3 unsigned int*)(&Bb[0][w * 512 + lane * 8]), 16, 0, 0);

    const int mrow = lane & 15;
    const int kq = (lane >> 4) * 8;
    for (int k0 = 0; k0 < 1024; k0 += 32) {
        const int cur = (k0 >> 5) & 1, nxt = cur ^ 1;
        __syncthreads();
        if (k0 + 32 < 1024) {
            const int k1 = k0 + 32;
#pragma unroll
            for (int s = 0; s < 2; ++s) {
                const int i = 2 * w + s;
                __builtin_amdgcn_global_load_lds(
                    (const AS1 unsigned int*)(A + (size_t)(t0 + i * 16 + srow) * 1024 + k1 + scol),
                    (AS3 unsigned int*)(&Ab[nxt][i * 512 + lane * 8]), 16, 0, 0);
            }
            __builtin_amdgcn_global_load_lds(
                (const AS1 unsigned int*)(W + (size_t)(n0 + w * 16 + srow) * 1024 + k1 + scol),
                (AS3 unsigned int*)(&Bb[nxt][w * 512 + lane * 8]), 16, 0, 0);
        }
        bf8_t af[4], bfr[2];
#pragma unroll
        for (int i = 0; i < 4; ++i)
            af[i] = *(const bf8_t*)(&Ab[cur][(wm + 16 * i + mrow) * 32 + kq]);
#pragma unroll
        for (int j = 0; j < 2; ++j)
            bfr[j] = *(const bf8_t*)(&Bb[cur][(wn + 16 * j + mrow) * 32 + kq]);
#pragma unroll
        for (int i = 0; i < 4; ++i)
#pragma unroll
            for (int j = 0; j < 2; ++j)
                acc[i][j] = __builtin_amdgcn_mfma_f32_16x16x32_bf16(
                    af[i], bfr[j], acc[i][j], 0, 0, 0);
    }
    const int crow = (lane >> 4) * 4;
    const int ccol = lane & 15;
#pragma unroll
    for (int i = 0; i < 4; ++i)
#pragma unroll
        for (int j = 0; j < 2; ++j)
#pragma unroll
            for (int u = 0; u < 4; ++u)
                out[(size_t)(t0 + wm + 16 * i + crow + u) * 1024
                    + n0 + wn + 16 * j + ccol] = acc[i][j][u];
}

__global__ __launch_bounds__(256) void gemm_bf16_3(
    const unsigned short* __restrict__ xr, const unsigned short* __restrict__ xk,
    const unsigned short* __restrict__ xv,
    const unsigned short* __restrict__ Wr, const unsigned short* __restrict__ Wk,
    const unsigned short* __restrict__ Wv,
    float* __restrict__ rB, float* __restrict__ kB, float* __restrict__ vB)
{
    const int z = blockIdx.z;
    const unsigned short* A = z == 0 ? xr : z == 1 ? xk : xv;
    const unsigned short* W = z == 0 ? Wr : z == 1 ? Wk : Wv;
    float* out = z == 0 ? rB : z == 1 ? kB : vB;
    gemm_core(A, W, out);
}

__global__ __launch_bounds__(256) void gemm_bf16(
    const unsigned short* __restrict__ A, const unsigned short* __restrict__ W,
    float* __restrict__ out)
{
    gemm_core(A, W, out);
}

// ---------------------------------------------------------------------------
// r12: K=128 MFMA GEMM for the g path: gB[t,i] = sum_c hg16[t,c]*g2t16[i,c].
// Same tile structure as gemm_core with row stride 128 and 4 K-steps.
// ---------------------------------------------------------------------------
__global__ __launch_bounds__(256) void gemm_g(
    const unsigned short* __restrict__ A, const unsigned short* __restrict__ W,
    float* __restrict__ out)
{
    __shared__ unsigned short Ab[2][128 * 32];
    __shared__ unsigned short Bb[2][64 * 32];
    const int tid = threadIdx.x;
    const int lane = tid & 63;
    const int w = tid >> 6;
    const int n0 = blockIdx.x * 64;
    const int t0 = blockIdx.y * 128;
    const int wm = (w & 1) * 64;
    const int wn = (w >> 1) * 32;
    const int srow = lane >> 2;
    const int scol = (lane & 3) * 8;

    f4_t acc[4][2];
#pragma unroll
    for (int i = 0; i < 4; ++i)
#pragma unroll
        for (int j = 0; j < 2; ++j)
            acc[i][j] = (f4_t){0.f, 0.f, 0.f, 0.f};

#pragma unroll
    for (int s = 0; s < 2; ++s) {
        const int i = 2 * w + s;
        __builtin_amdgcn_global_load_lds(
            (const AS1 unsigned int*)(A + (size_t)(t0 + i * 16 + srow) * 128 + scol),
            (AS3 unsigned int*)(&Ab[0][i * 512 + lane * 8]), 16, 0, 0);
    }
    __builtin_amdgcn_global_load_lds(
        (const AS1 unsigned int*)(W + (size_t)(n0 + w * 16 + srow) * 128 + scol),
        (AS3 unsigned int*)(&Bb[0][w * 512 + lane * 8]), 16, 0, 0);

    const int mrow = lane & 15;
    const int kq = (lane >> 4) * 8;
    for (int k0 = 0; k0 < 128; k0 += 32) {
        const int cur = (k0 >> 5) & 1, nxt = cur ^ 1;
        __syncthreads();
        if (k0 + 32 < 128) {
            const int k1 = k0 + 32;
#pragma unroll
            for (int s = 0; s < 2; ++s) {
                const int i = 2 * w + s;
                __builtin_amdgcn_global_load_lds(
                    (const AS1 unsigned int*)(A + (size_t)(t0 + i * 16 + srow) * 128 + k1 + scol),
                    (AS3 unsigned int*)(&Ab[nxt][i * 512 + lane * 8]), 16, 0, 0);
            }
            __builtin_amdgcn_global_load_lds(
                (const AS1 unsigned int*)(W + (size_t)(n0 + w * 16 + srow) * 128 + k1 + scol),
                (AS3 unsigned int*)(&Bb[nxt][w * 512 + lane * 8]), 16, 0, 0);
        }
        bf8_t af[4], bfr[2];
#pragma unroll
        for (int i = 0; i < 4; ++i)
            af[i] = *(const bf8_t*)(&Ab[cur][(wm + 16 * i + mrow) * 32 + kq]);
#pragma unroll
        for (int j = 0; j < 2; ++j)
            bfr[j] = *(const bf8_t*)(&Bb[cur][(wn + 16 * j + mrow) * 32 + kq]);
#pragma unroll
        for (int i = 0; i < 4; ++i)
#pragma unroll
            for (int j = 0; j < 2; ++j)
                acc[i][j] = __builtin_amdgcn_mfma_f32_16x16x32_bf16(
                    af[i], bfr[j], acc[i][j], 0, 0, 0);
    }
    const int crow = (lane >> 4) * 4;
    const int ccol = lane & 15;
#pragma unroll
    for (int i = 0; i < 4; ++i)
#pragma unroll
        for (int j = 0; j < 2; ++j)
#pragma unroll
            for (int u = 0; u < 4; ++u)
                out[(size_t)(t0 + wm + 16 * i + crow + u) * 1024
                    + n0 + wn + 16 * j + ccol] = acc[i][j][u];
}

// ---------------------------------------------------------------------------
// Fused LoRA stage-1 via MFMA: z = 0:w(tanh,N=64) 1:a(N=64) 2:v(N=32) 3:g(sig,N=128)
// r12: z==3 (g) writes BF16 into hg16 (feeds the MFMA g-GEMM).
// ---------------------------------------------------------------------------
__global__ __launch_bounds__(256) void lora1m(
    const unsigned short* __restrict__ xw, const unsigned short* __restrict__ xa,
    const unsigned short* __restrict__ xv, const unsigned short* __restrict__ xg,
    const unsigned short* __restrict__ lw16,
    float* __restrict__ hw, float* __restrict__ ha, float* __restrict__ hv,
    unsigned short* __restrict__ hg16)
{
    const int z = blockIdx.z;
    const unsigned short* A = z == 0 ? xw : z == 1 ? xa : z == 2 ? xv : xg;
    const unsigned short* W = lw16 + (size_t)(z == 0 ? 0 : z == 1 ? 64 : z == 2 ? 128 : 192) * 1024;
    float* out = z == 0 ? hw : z == 1 ? ha : hv;
    const int N  = z == 3 ? 128 : z == 2 ? 32 : 64;
    const int Ns = z == 3 ? 128 : 64;
    const int n0 = blockIdx.x * 64;
    if (n0 >= Ns) return;

    __shared__ unsigned short Ab[2][128 * 32];
    __shared__ unsigned short Bb[2][64 * 32];
    const int tid = threadIdx.x;
    const int lane = tid & 63;
    const int w = tid >> 6;
    const int t0 = blockIdx.y * 128;
    const int wm = (w & 1) * 64;
    const int wn = (w >> 1) * 32;
    const int srow = lane >> 2;
    const int scol = (lane & 3) * 8;

    f4_t acc[4][2];
#pragma unroll
    for (int i = 0; i < 4; ++i)
#pragma unroll
        for (int j = 0; j < 2; ++j)
            acc[i][j] = (f4_t){0.f, 0.f, 0.f, 0.f};

#pragma unroll
    for (int s = 0; s < 2; ++s) {
        const int i = 2 * w + s;
        __builtin_amdgcn_global_load_lds(
            (const AS1 unsigned int*)(A + (size_t)(t0 + i * 16 + srow) * 1024 + scol),
            (AS3 unsigned int*)(&Ab[0][i * 512 + lane * 8]), 16, 0, 0);
    }
    __builtin_amdgcn_global_load_lds(
        (const AS1 unsigned int*)(W + (size_t)(n0 + w * 16 + srow) * 1024 + scol),
        (AS3 unsigned int*)(&Bb[0][w * 512 + lane * 8]), 16, 0, 0);

    const int mrow = lane & 15;
    const int kq = (lane >> 4) * 8;
    for (int k0 = 0; k0 < 1024; k0 += 32) {
        const int cur = (k0 >> 5) & 1, nxt = cur ^ 1;
        __syncthreads();
        if (k0 + 32 < 1024) {
            const int k1 = k0 + 32;
#pragma unroll
            for (int s = 0; s < 2; ++s) {
                const int i = 2 * w + s;
                __builtin_amdgcn_global_load_lds(
                    (const AS1 unsigned int*)(A + (size_t)(t0 + i * 16 + srow) * 1024 + k1 + scol),
                    (AS3 unsigned int*)(&Ab[nxt][i * 512 + lane * 8]), 16, 0, 0);
            }
            __builtin_amdgcn_global_load_lds(
                (const AS1 unsigned int*)(W + (size_t)(n0 + w * 16 + srow) * 1024 + k1 + scol),
                (AS3 unsigned int*)(&Bb[nxt][w * 512 + lane * 8]), 16, 0, 0);
        }
        bf8_t af[4], bfr[2];
#pragma unroll
        for (int i = 0; i < 4; ++i)
            af[i] = *(const bf8_t*)(&Ab[cur][(wm + 16 * i + mrow) * 32 + kq]);
#pragma unroll
        for (int j = 0; j < 2; ++j)
            bfr[j] = *(const bf8_t*)(&Bb[cur][(wn + 16 * j + mrow) * 32 + kq]);
#pragma unroll
        for (int i = 0; i < 4; ++i)
#pragma unroll
            for (int j = 0; j < 2; ++j)
                acc[i][j] = __builtin_amdgcn_mfma_f32_16x16x32_bf16(
                    af[i], bfr[j], acc[i][j], 0, 0, 0);
    }
    const int crow = (lane >> 4) * 4;
    const int ccol = lane & 15;
#pragma unroll
    for (int i = 0; i < 4; ++i)
#pragma unroll
        for (int j = 0; j < 2; ++j) {
            const int col = n0 + wn + 16 * j + ccol;
            if (col < N) {
#pragma unroll
                for (int u = 0; u < 4; ++u) {
                    float vv = acc[i][j][u];
                    if (z == 0) {
                        vv = tanhf(vv);
                        out[(size_t)(t0 + wm + 16 * i + crow + u) * N + col] = vv;
                    } else if (z == 3) {
                        vv = sigf(vv);
                        hg16[(size_t)(t0 + wm + 16 * i + crow + u) * 128 + col] = f2bf(vv);
                    } else {
                        out[(size_t)(t0 + wm + 16 * i + crow + u) * N + col] = vv;
                    }
                }
            }
        }
}

// ---------------------------------------------------------------------------
// Fused LoRA-2 (w/a/v) + k post-process + PAIR-COMPOSED packet packing.
// r12: g matvec removed (now MFMA gemm_g); zoff reverted (r11 regression).
// Packet layout (768 floats) unchanged from r4.
// ---------------------------------------------------------------------------
#define TOK 4
__global__ __launch_bounds__(256) void lora2f(
    const float* __restrict__ hwB, const float* __restrict__ haB,
    const float* __restrict__ hvB,
    const float* __restrict__ w2, const float* __restrict__ a2,
    const float* __restrict__ v2,
    const float* __restrict__ w0, const float* __restrict__ a0,
    const float* __restrict__ v0,
    const float* __restrict__ k_k, const float* __restrict__ k_a,
    const float* __restrict__ v_first, const float* __restrict__ rB,
    float* __restrict__ kB, float* __restrict__ vB,
    float* __restrict__ pk)
{
    const int tid = threadIdx.x;
    const int t0 = blockIdx.y * TOK;
    const int i  = blockIdx.x * 256 + tid;
    const int h  = i >> 6;
    const int j  = i & 63;

    float av[TOK], ew[TOK], vf[TOK];
    { // a = sigmoid(a0 + ha@a2)
        float acc[TOK];
        const float b0 = a0[i];
#pragma unroll
        for (int tt = 0; tt < TOK; ++tt) acc[tt] = b0;
        for (int jj = 0; jj < 64; jj += 4) {
            const float q0 = a2[(size_t)(jj + 0) * C_DIM + i];
            const float q1 = a2[(size_t)(jj + 1) * C_DIM + i];
            const float q2 = a2[(size_t)(jj + 2) * C_DIM + i];
            const float q3 = a2[(size_t)(jj + 3) * C_DIM + i];
#pragma unroll
            for (int tt = 0; tt < TOK; ++tt) {
                float4 h4 = *(const float4*)(haB + (size_t)(t0 + tt) * 64 + jj);
                acc[tt] = fmaf(h4.x, q0, acc[tt]);
                acc[tt] = fmaf(h4.y, q1, acc[tt]);
                acc[tt] = fmaf(h4.z, q2, acc[tt]);
                acc[tt] = fmaf(h4.w, q3, acc[tt]);
            }
        }
#pragma unroll
        for (int tt = 0; tt < TOK; ++tt) av[tt] = sigf(acc[tt]);
    }
    { // exp(w)
        float acc[TOK];
        const float b0 = w0[i];
#pragma unroll
        for (int tt = 0; tt < TOK; ++tt) acc[tt] = b0;
        for (int jj = 0; jj < 64; jj += 4) {
            const float q0 = w2[(size_t)(jj + 0) * C_DIM + i];
            const float q1 = w2[(size_t)(jj + 1) * C_DIM + i];
            const float q2 = w2[(size_t)(jj + 2) * C_DIM + i];
            const float q3 = w2[(size_t)(jj + 3) * C_DIM + i];
#pragma unroll
            for (int tt = 0; tt < TOK; ++tt) {
                float4 h4 = *(const float4*)(hwB + (size_t)(t0 + tt) * 64 + jj);
                acc[tt] = fmaf(h4.x, q0, acc[tt]);
                acc[tt] = fmaf(h4.y, q1, acc[tt]);
                acc[tt] = fmaf(h4.z, q2, acc[tt]);
                acc[tt] = fmaf(h4.w, q3, acc[tt]);
            }
        }
#pragma unroll
        for (int tt = 0; tt < TOK; ++tt)
            ew[tt] = __expf(-0.6065306597126334f * sigf(acc[tt]));
    }
    { // v mix
        float acc[TOK];
        const float b0 = v0[i];
#pragma unroll
        for (int tt = 0; tt < TOK; ++tt) acc[tt] = b0;
        for (int jj = 0; jj < 32; jj += 4) {
            const float q0 = v2[(size_t)(jj + 0) * C_DIM + i];
            const float q1 = v2[(size_t)(jj + 1) * C_DIM + i];
            const float q2 = v2[(size_t)(jj + 2) * C_DIM + i];
            const float q3 = v2[(size_t)(jj + 3) * C_DIM + i];
#pragma unroll
            for (int tt = 0; tt < TOK; ++tt) {
                float4 h4 = *(const float4*)(hvB + (size_t)(t0 + tt) * 32 + jj);
                acc[tt] = fmaf(h4.x, q0, acc[tt]);
                acc[tt] = fmaf(h4.y, q1, acc[tt]);
                acc[tt] = fmaf(h4.z, q2, acc[tt]);
                acc[tt] = fmaf(h4.w, q3, acc[tt]);
            }
        }
#pragma unroll
        for (int tt = 0; tt < TOK; ++tt) {
            const size_t gi = (size_t)(t0 + tt) * C_DIM + i;
            const float s = sigf(acc[tt]);
            const float vr = vB[gi];
            vf[tt] = vr + (v_first[gi] - vr) * s;
            vB[gi] = vf[tt];
        }
    }
    // k post-process + pair-composed packing
    const float kkw = k_k[i], kaw = k_a[i];
    const size_t pbase = (size_t)h * 1024 * PAIR_F;
    for (int pt = 0; pt < TOK / 2; ++pt) {
        float r_[2], e_[2], kf_[2], v_[2], aa_[2], bb_[2];
#pragma unroll
        for (int u = 0; u < 2; ++u) {
            const int tt = 2 * pt + u;
            const size_t gi = (size_t)(t0 + tt) * C_DIM + i;
            const float kraw = kB[gi];
            const float kn = kraw * kkw;
            const float ss = red64(kn * kn);
            const float sc = 1.f / fmaxf(sqrtf(ss), 1e-12f);
            const float kk = kn * sc;
            const float a_ = av[tt];
            const float kf = kraw * (1.f + (a_ - 1.f) * kaw);
            kB[gi] = kf;
            r_[u] = rB[gi];
            e_[u] = ew[tt];
            kf_[u] = kf;
            v_[u] = vf[tt];
            aa_[u] = -kk;
            bb_[u] = kk * a_;
        }
        const float E   = e_[0] * e_[1];
        const float A2e = e_[0] * aa_[1];
        const float B1e = bb_[0] * e_[1];
        const float K1e = kf_[0] * e_[1];
        const float R1e = e_[0] * r_[0];
        const float cba = red64(bb_[0] * aa_[1]);
        const float cka = red64(kf_[0] * aa_[1]);
        const float cbr = red64(bb_[0] * r_[0]);
        const float ckr = red64(kf_[0] * r_[0]);
        const float cbr2  = red64(B1e * r_[1]);
        const float ckr2  = red64(K1e * r_[1]);
        const float cb2r2 = red64(bb_[1] * r_[1]);
        const float ck2r2 = red64(kf_[1] * r_[1]);
        float* p = pk + pbase + (size_t)(blockIdx.y * (TOK / 2) + pt) * PAIR_F;
        p[j]        = E;
        p[64 + j]   = aa_[0];
        p[128 + j]  = A2e;
        p[192 + j]  = B1e;
        p[256 + j]  = K1e;
        p[320 + j]  = bb_[1];
        p[384 + j]  = kf_[1];
        p[448 + j]  = R1e;
        p[512 + j]  = E * r_[1];          // R2e = E ⊙ R2
        p[576 + 2 * j]     = v_[0];       // vv interleaved
        p[576 + 2 * j + 1] = v_[1];
        if (j == 0) {
            p[704] = cba;  p[705] = cka;  p[706] = cbr;  p[707] = ckr;
            p[708] = cbr2; p[709] = ckr2; p[710] = cb2r2; p[711] = ck2r2;
        }
    }
}

// ---------------------------------------------------------------------------
// CHUNKED SCAN (r9 structure, unchanged): NCH=32/CPAIR=32, 2048 waves per
// scan phase (2 waves/SIMD); Pbuf aliases y region; CSbuf in-place combine.
// ---------------------------------------------------------------------------
struct SlotPC {
    float4 E, A1, A2e, B1e, K1e, B2, K2;
    float4 vva, vvb;   // {v1,v2} for rows rbase..rbase+3
    float4 sc;         // cba, cka, cbr, ckr (only x,y used here)
};

static __device__ __forceinline__ void slot_load_pc(
    SlotPC& K, const float* __restrict__ p, int j0, int rb2)
{
    K.E   = *(const float4*)(p + j0);
    K.A1  = *(const float4*)(p + 64 + j0);
    K.A2e = *(const float4*)(p + 128 + j0);
    K.B1e = *(const float4*)(p + 192 + j0);
    K.K1e = *(const float4*)(p + 256 + j0);
    K.B2  = *(const float4*)(p + 320 + j0);
    K.K2  = *(const float4*)(p + 384 + j0);
    K.vva = *(const float4*)(p + 576 + rb2);
    K.vvb = *(const float4*)(p + 576 + rb2 + 4);
    K.sc  = *(const float4*)(p + 704);
}

static __device__ __forceinline__ void pair_pc(
    f2_t* PSl, f2_t* PSh, f2_t* CSl, f2_t* CSh, const SlotPC& K)
{
    float pu1[4], pu2[4], cu1[4], cu2[4];
#pragma unroll
    for (int r = 0; r < 4; ++r) {
        pu1[r] = red16(dot4pk(PSl[r], PSh[r], K.A1));
        pu2[r] = red16(dot4pk(PSl[r], PSh[r], K.A2e));
        cu1[r] = red16(dot4pk(CSl[r], CSh[r], K.A1));
        cu2[r] = red16(dot4pk(CSl[r], CSh[r], K.A2e));
    }
#pragma unroll
    for (int r = 0; r < 4; ++r) {
        { // P update: v-terms exactly zero -> dropped (bitwise identical)
            const float sa1 = pu1[r];
            const float sa2 = fmaf(sa1, K.sc.x, pu2[r]);
            const f2_t sa1v = f2bc(sa1), sa2v = f2bc(sa2);
            f2_t nl = PSl[r] * lo2(K.E), nh = PSh[r] * hi2(K.E);
            nl = fma2(sa1v, lo2(K.B1e), nl); nh = fma2(sa1v, hi2(K.B1e), nh);
            nl = fma2(sa2v, lo2(K.B2), nl);  nh = fma2(sa2v, hi2(K.B2), nh);
            PSl[r] = nl; PSh[r] = nh;
        }
        { // C update: full recurrence from zero init
            const float v1 = r == 0 ? K.vva.x : r == 1 ? K.vva.z
                           : r == 2 ? K.vvb.x : K.vvb.z;
            const float v2 = r == 0 ? K.vva.y : r == 1 ? K.vva.w
                           : r == 2 ? K.vvb.y : K.vvb.w;
            const float sa1 = cu1[r];
            const float sa2 = fmaf(v1, K.sc.y, fmaf(sa1, K.sc.x, cu2[r]));
            const f2_t sa1v = f2bc(sa1), sa2v = f2bc(sa2);
            const f2_t v1v = f2bc(v1), v2v = f2bc(v2);
            f2_t nl = CSl[r] * lo2(K.E), nh = CSh[r] * hi2(K.E);
            nl = fma2(sa1v, lo2(K.B1e), nl); nh = fma2(sa1v, hi2(K.B1e), nh);
            nl = fma2(v1v, lo2(K.K1e), nl);  nh = fma2(v1v, hi2(K.K1e), nh);
            nl = fma2(sa2v, lo2(K.B2), nl);  nh = fma2(sa2v, hi2(K.B2), nh);
            nl = fma2(v2v, lo2(K.K2), nl);   nh = fma2(v2v, hi2(K.K2), nh);
            CSl[r] = nl; CSh[r] = nh;
        }
    }
}

// grid: b = h + 16*w + 64*c  (w stride 16 => same (h,c) on same XCD mod 8)
__global__ __launch_bounds__(64, 1) void pc_fused(
    const float* __restrict__ pk, float* __restrict__ Pbuf,
    float* __restrict__ Cbuf)
{
    const int b = blockIdx.x;
    const int h = b & 15;
    const int w = (b >> 4) & 3;
    const int c = b >> 6;
    const int l = threadIdx.x;
    const int q = l >> 4;
    const int j0 = (l & 15) * 4;
    const int rbase = w * 16 + q * 4;
    const int rb2 = 2 * rbase;
    const float* hbase = pk + ((size_t)h * 1024 + (size_t)c * CPAIR) * PAIR_F;

    f2_t PSl[4], PSh[4], CSl[4], CSh[4];
#pragma unroll
    for (int r = 0; r < 4; ++r) {
        const int row = rbase + r;
        PSl[r] = (f2_t){j0 == row ? 1.f : 0.f, j0 + 1 == row ? 1.f : 0.f};
        PSh[r] = (f2_t){j0 + 2 == row ? 1.f : 0.f, j0 + 3 == row ? 1.f : 0.f};
        CSl[r] = (f2_t){0.f, 0.f};
        CSh[r] = (f2_t){0.f, 0.f};
    }

    SlotPC s0, s1, s2, s3;
    slot_load_pc(s0, hbase + 0 * PAIR_F, j0, rb2);
    slot_load_pc(s1, hbase + 1 * PAIR_F, j0, rb2);
    slot_load_pc(s2, hbase + 2 * PAIR_F, j0, rb2);
    slot_load_pc(s3, hbase + 3 * PAIR_F, j0, rb2);
    __builtin_amdgcn_sched_barrier(0);

    for (int i = 0; i < CPAIR - 4; i += 4) {
        const float* pl = hbase + (size_t)(i + 4) * PAIR_F;
        pair_pc(PSl, PSh, CSl, CSh, s0); slot_load_pc(s0, pl + 0 * PAIR_F, j0, rb2);
        __builtin_amdgcn_sched_barrier(0);
        pair_pc(PSl, PSh, CSl, CSh, s1); slot_load_pc(s1, pl + 1 * PAIR_F, j0, rb2);
        __builtin_amdgcn_sched_barrier(0);
        pair_pc(PSl, PSh, CSl, CSh, s2); slot_load_pc(s2, pl + 2 * PAIR_F, j0, rb2);
        __builtin_amdgcn_sched_barrier(0);
        pair_pc(PSl, PSh, CSl, CSh, s3); slot_load_pc(s3, pl + 3 * PAIR_F, j0, rb2);
        __builtin_amdgcn_sched_barrier(0);
    }
    pair_pc(PSl, PSh, CSl, CSh, s0);
    pair_pc(PSl, PSh, CSl, CSh, s1);
    pair_pc(PSl, PSh, CSl, CSh, s2);
    pair_pc(PSl, PSh, CSl, CSh, s3);

    const size_t cb64 = ((size_t)h * NCH + c) * 4096;
#pragma unroll
    for (int r = 0; r < 4; ++r) {
        *(float4*)(Pbuf + cb64 + (size_t)(rbase + r) * 64 + j0) =
            (float4){PSl[r].x, PSl[r].y, PSh[r].x, PSh[r].y};
        *(float4*)(Cbuf + cb64 + (size_t)(rbase + r) * 64 + j0) =
            (float4){CSl[r].x, CSl[r].y, CSh[r].x, CSh[r].y};
    }
}

// Phase 2: serial chunk combine S <- S*P_c + C_c. IN-PLACE Scbuf.
__global__ __launch_bounds__(64) void combine(
    const float* __restrict__ Pbuf, float* __restrict__ CSbuf,
    const float* __restrict__ init_state)
{
    const int b = blockIdx.x;
    const int h = b & 15;
    const int g = b >> 4;
    const int l = threadIdx.x;
    const int vl = l >> 4;
    const int vidx = g * 4 + vl;
    const int j0 = (l & 15) * 4;
    __shared__ __align__(16) float Pl[64 * 64];
    __shared__ __align__(16) float sl[4 * 64];

    float4 s = *(const float4*)(init_state + h * 4096 + vidx * 64 + j0);
    for (int c = 0; c < NCH; ++c) {
        const size_t cbase = ((size_t)h * NCH + c) * 4096;
        float* cp = CSbuf + cbase + (size_t)vidx * 64 + j0;
        float4 Cv = *(const float4*)cp;   // load C_c FIRST
        *(float4*)cp = s;                 // then store chunk-start state
        const float* Psrc = Pbuf + cbase;
#pragma unroll
        for (int t = 0; t < 16; ++t)
            *(float4*)(&Pl[t * 256 + l * 4]) = *(const float4*)(Psrc + t * 256 + l * 4);
        *(float4*)(&sl[vl * 64 + j0]) = s;
        __syncthreads();
        f2_t al = {Cv.x, Cv.y}, ah = {Cv.z, Cv.w};
        for (int k = 0; k < 64; ++k) {
            const float sk = sl[vl * 64 + k];
            float4 Pr = *(const float4*)(&Pl[k * 64 + j0]);
            al = fma2(f2bc(sk), lo2(Pr), al);
            ah = fma2(f2bc(sk), hi2(Pr), ah);
        }
        s = (float4){al.x, al.y, ah.x, ah.y};
        __syncthreads();
    }
}

// ---- output scan: 4 rows/lane-group, 2-slot pinned ring -------------------
struct SlotO {
    float4 E, A1, A2e, B1e, K1e, B2, K2, R1e, R2e;
    float4 vva, vvb;
    float4 sc, sc2;
};

static __device__ __forceinline__ void slot_load_o(
    SlotO& K, const float* __restrict__ p, int j0, int rb2)
{
    K.E   = *(const float4*)(p + j0);
    K.A1  = *(const float4*)(p + 64 + j0);
    K.A2e = *(const float4*)(p + 128 + j0);
    K.B1e = *(const float4*)(p + 192 + j0);
    K.K1e = *(const float4*)(p + 256 + j0);
    K.B2  = *(const float4*)(p + 320 + j0);
    K.K2  = *(const float4*)(p + 384 + j0);
    K.R1e = *(const float4*)(p + 448 + j0);
    K.R2e = *(const float4*)(p + 512 + j0);
    K.vva = *(const float4*)(p + 576 + rb2);
    K.vvb = *(const float4*)(p + 576 + rb2 + 4);
    K.sc  = *(const float4*)(p + 704);
    K.sc2 = *(const float4*)(p + 708);
}

static __device__ __forceinline__ void pair_out(
    f2_t* Sl, f2_t* Sh, const SlotO& K, float4& o1v, float4& o2v)
{
    float u1[4], u2[4], op[4], oz[4];
#pragma unroll
    for (int r = 0; r < 4; ++r) {
        u1[r] = red16(dot4pk(Sl[r], Sh[r], K.A1));
        u2[r] = red16(dot4pk(Sl[r], Sh[r], K.A2e));
        op[r] = red16(dot4pk(Sl[r], Sh[r], K.R1e));
        oz[r] = red16(dot4pk(Sl[r], Sh[r], K.R2e));
    }
    float o1a[4], o2a[4];
#pragma unroll
    for (int r = 0; r < 4; ++r) {
        const float v1 = r == 0 ? K.vva.x : r == 1 ? K.vva.z
                       : r == 2 ? K.vvb.x : K.vvb.z;
        const float v2 = r == 0 ? K.vva.y : r == 1 ? K.vva.w
                       : r == 2 ? K.vvb.y : K.vvb.w;
        const float sa1 = u1[r];
        const float sa2 = fmaf(v1, K.sc.y, fmaf(sa1, K.sc.x, u2[r]));
        o1a[r] = fmaf(v1, K.sc.w, fmaf(sa1, K.sc.z, op[r]));
        o2a[r] = fmaf(v2, K.sc2.w, fmaf(sa2, K.sc2.z,
                 fmaf(v1, K.sc2.y, fmaf(sa1, K.sc2.x, oz[r]))));
        const f2_t sa1v = f2bc(sa1), sa2v = f2bc(sa2);
        const f2_t v1v = f2bc(v1), v2v = f2bc(v2);
        f2_t nl = Sl[r] * lo2(K.E), nh = Sh[r] * hi2(K.E);
        nl = fma2(sa1v, lo2(K.B1e), nl); nh = fma2(sa1v, hi2(K.B1e), nh);
        nl = fma2(v1v, lo2(K.K1e), nl);  nh = fma2(v1v, hi2(K.K1e), nh);
        nl = fma2(sa2v, lo2(K.B2), nl);  nh = fma2(sa2v, hi2(K.B2), nh);
        nl = fma2(v2v, lo2(K.K2), nl);   nh = fma2(v2v, hi2(K.K2), nh);
        Sl[r] = nl; Sh[r] = nh;
    }
    o1v = (float4){o1a[0], o1a[1], o1a[2], o1a[3]};
    o2v = (float4){o2a[0], o2a[1], o2a[2], o2a[3]};
}

__global__ __launch_bounds__(64, 1) void out_scan(
    const float* __restrict__ pk, const float* __restrict__ Scbuf,
    float* __restrict__ y)
{
    const int b = blockIdx.x;
    const int h = b & 15;
    const int w = (b >> 4) & 3;
    const int c = b >> 6;
    const int l = threadIdx.x;
    const int q = l >> 4;
    const int j0 = (l & 15) * 4;
    const int rbase = w * 16 + q * 4;
    const int rb2 = 2 * rbase;
    const int cb = h * 64;
    const float* hbase = pk + ((size_t)h * 1024 + (size_t)c * CPAIR) * PAIR_F;
    const size_t cb64 = ((size_t)h * NCH + c) * 4096;

    f2_t Sl[4], Sh[4];
#pragma unroll
    for (int r = 0; r < 4; ++r) {
        float4 S4 = *(const float4*)(Scbuf + cb64 + (size_t)(rbase + r) * 64 + j0);
        Sl[r] = (f2_t){S4.x, S4.y};
        Sh[r] = (f2_t){S4.z, S4.w};
    }

    SlotO s0, s1;
    slot_load_o(s0, hbase + 0 * PAIR_F, j0, rb2);
    slot_load_o(s1, hbase + 1 * PAIR_F, j0, rb2);
    __builtin_amdgcn_sched_barrier(0);

    const bool wr = (l & 15) == 0;
    const int pi0 = c * CPAIR;
    float4 o1v, o2v;
#define OUT_STORE(pidx)                                                       \
    if (wr) {                                                                 \
        float* yp = y + (size_t)(2 * (pidx)) * C_DIM + cb + rbase;            \
        *(float4*)yp = o1v;                                                   \
        *(float4*)(yp + C_DIM) = o2v;                                         \
    }
    for (int i = 0; i < CPAIR - 2; i += 2) {
        pair_out(Sl, Sh, s0, o1v, o2v);
        slot_load_o(s0, hbase + (size_t)(i + 2) * PAIR_F, j0, rb2);
        __builtin_amdgcn_sched_barrier(0);
        OUT_STORE(pi0 + i)
        pair_out(Sl, Sh, s1, o1v, o2v);
        if (i + 3 < CPAIR)
            slot_load_o(s1, hbase + (size_t)(i + 3) * PAIR_F, j0, rb2);
        __builtin_amdgcn_sched_barrier(0);
        OUT_STORE(pi0 + i + 1)
    }
    pair_out(Sl, Sh, s0, o1v, o2v);
    OUT_STORE(pi0 + CPAIR - 2)
    pair_out(Sl, Sh, s1, o1v, o2v);
    OUT_STORE(pi0 + CPAIR - 1)
#undef OUT_STORE
}

// ---------------------------------------------------------------------------
// GroupNorm + bonus + *g ; writes bf16 (xo*g) for the final MFMA GEMM.
// ---------------------------------------------------------------------------
__global__ __launch_bounds__(256) void gn_bonus(
    const float* __restrict__ y, const float* __restrict__ rb,
    const float* __restrict__ kb, const float* __restrict__ vb,
    const float* __restrict__ gb, const float* __restrict__ r_k,
    const float* __restrict__ lnw, const float* __restrict__ lnb,
    unsigned short* __restrict__ yg)
{
    const int t = blockIdx.x, tid = threadIdx.x;
    const int c0 = tid << 2;
    const size_t base = (size_t)t * C_DIM + c0;
    float4 yv = *(const float4*)(y + base);
    float sum = yv.x + yv.y + yv.z + yv.w;
    float ss  = yv.x * yv.x + yv.y * yv.y + yv.z * yv.z + yv.w * yv.w;
    float4 rv = *(const float4*)(rb + base);
    float4 kv = *(const float4*)(kb + base);
    float4 rkv = *(const float4*)(r_k + c0);
    float dot = rv.x * kv.x * rkv.x + rv.y * kv.y * rkv.y +
                rv.z * kv.z * rkv.z + rv.w * kv.w * rkv.w;
#pragma unroll
    for (int m = 1; m <= 8; m <<= 1) {
        sum += __shfl_xor(sum, m);
        ss  += __shfl_xor(ss, m);
        dot += __shfl_xor(dot, m);
    }
    const float mu = sum * 0.015625f;
    const float var = ss * 0.015625f - mu * mu;
    const float rstd = rsqrtf(var + 0.00064f);
    float4 wv = *(const float4*)(lnw + c0);
    float4 bv = *(const float4*)(lnb + c0);
    float4 vv = *(const float4*)(vb + base);
    float4 gv = *(const float4*)(gb + base);
    ushort4 o;
    o.x = f2bf(((yv.x - mu) * rstd * wv.x + bv.x + dot * vv.x) * gv.x);
    o.y = f2bf(((yv.y - mu) * rstd * wv.y + bv.y + dot * vv.y) * gv.y);
    o.z = f2bf(((yv.z - mu) * rstd * wv.z + bv.z + dot * vv.z) * gv.z);
    o.w = f2bf(((yv.w - mu) * rstd * wv.w + bv.w + dot * vv.w) * gv.w);
    *(ushort4*)(yg + base) = o;
}

// ---------------------------------------------------------------------------
extern "C" void kernel_launch(void* const* d_in, const int* in_sizes, int n_in,
                              void* d_out, int out_size, void* d_ws, size_t ws_size,
                              hipStream_t stream)
{
    (void)in_sizes; (void)n_in; (void)out_size; (void)ws_size;
    const float* x       = (const float*)d_in[0];
    const float* v_first = (const float*)d_in[1];
    const float* x_prev  = (const float*)d_in[2];
    const float* init_st = (const float*)d_in[3];
    const float* x_r = (const float*)d_in[4];
    const float* x_w = (const float*)d_in[5];
    const float* x_k = (const float*)d_in[6];
    const float* x_v = (const float*)d_in[7];
    const float* x_a = (const float*)d_in[8];
    const float* x_g = (const float*)d_in[9];
    const float* w0  = (const float*)d_in[10];
    const float* a0  = (const float*)d_in[11];
    const float* v0  = (const float*)d_in[12];
    const float* k_k = (const float*)d_in[13];
    const float* k_a = (const float*)d_in[14];
    const float* w1  = (const float*)d_in[15];
    const float* w2  = (const float*)d_in[16];
    const float* a1  = (const float*)d_in[17];
    const float* a2  = (const float*)d_in[18];
    const float* v1  = (const float*)d_in[19];
    const float* v2  = (const float*)d_in[20];
    const float* g1  = (const float*)d_in[21];
    const float* g2  = (const float*)d_in[22];
    const float* r_k = (const float*)d_in[23];
    const float* Wr  = (const float*)d_in[24];
    const float* Wk  = (const float*)d_in[25];
    const float* Wv  = (const float*)d_in[26];
    const float* Wo  = (const float*)d_in[27];
    const float* ln_w = (const float*)d_in[28];
    const float* ln_b = (const float*)d_in[29];

    float* out = (float*)d_out;
    float* ws  = (float*)d_ws;
    const size_t NE = (size_t)T_LEN * C_DIM;   // 2M
    const size_t WE = (size_t)C_DIM * C_DIM;   // 1M
    float* rB  = ws;
    float* kB  = ws + NE;
    float* vB  = ws + 2 * NE;
    float* gB  = ws + 3 * NE;
    float* hwB = ws + 4 * NE;                  // T*64
    float* haB = hwB + (size_t)T_LEN * 64;
    float* hvB = haB + (size_t)T_LEN * 64;
    float* pk  = ws + 4 * NE + NE / 2;         // 6*NE floats (16*1024*768)
    unsigned short* b16 = (unsigned short*)(ws + 10 * NE + NE / 2);
    unsigned short* xr16 = b16;                // NE shorts
    unsigned short* xk16 = b16 + NE;
    unsigned short* xv16 = b16 + 2 * NE;
    unsigned short* Wr16 = b16 + 3 * NE;       // 4*WE shorts
    unsigned short* Wk16 = Wr16 + WE;
    unsigned short* Wv16 = Wr16 + 2 * WE;
    unsigned short* Wo16 = Wr16 + 3 * WE;
    unsigned short* yg16 = b16 + 3 * NE + 4 * WE;  // NE shorts
    unsigned short* lw16 = yg16 + NE;              // 320K shorts (LoRA weights)
    unsigned short* hg16 = lw16 + (size_t)320 * 1024;   // T*128 shorts (r12)
    unsigned short* g2t16 = hg16 + (size_t)T_LEN * 128; // 1024*128 shorts (r12)
    // xw/xa/xg bf16 live in the pk region (pk written later by lora2f)
    unsigned short* xw16 = (unsigned short*)pk;
    unsigned short* xa16 = xw16 + NE;
    unsigned short* xg16 = xw16 + 2 * NE;
    // yB aliases xr16+xk16 (consumed by gemms before the scan writes it)
    float* yB = (float*)xr16;
    // Chunk-scan buffers (NCH=32 -> 2M floats each):
    //   Pbuf  <- y region (xr16+xk16)
    //   CSbuf <- xv16+Wr16+Wk16 (2M floats exactly; dead after gemm3/lora1m)
    float* Pbuf  = (float*)xr16;   // 16h x 32c x 64 x 64 = 2M floats
    float* CSbuf = (float*)xv16;   // 2M floats (xv16..Wk16)

    wcvtall<<<4896, 256, 0, stream>>>(Wr, Wk, Wv, Wo, w1, a1, v1, g1, g2,
                                      Wr16, lw16, g2t16);
    xcvt<<<T_LEN, 256, 0, stream>>>(x, x_prev, x_r, x_k, x_v, x_w, x_a, x_g,
                                    xr16, xk16, xv16, xw16, xa16, xg16);

    gemm_bf16_3<<<dim3(16, 16, 3), 256, 0, stream>>>(
        xr16, xk16, xv16, Wr16, Wk16, Wv16, rB, kB, vB);

    lora1m<<<dim3(2, 16, 4), 256, 0, stream>>>(
        xw16, xa16, xv16, xg16, lw16, hwB, haB, hvB, hg16);

    gemm_g<<<dim3(16, 16), 256, 0, stream>>>(hg16, g2t16, gB);

    lora2f<<<dim3(4, T_LEN / TOK), 256, 0, stream>>>(
        hwB, haB, hvB, w2, a2, v2, w0, a0, v0,
        k_k, k_a, v_first, rB, kB, vB, pk);

    pc_fused<<<16 * 4 * NCH, 64, 0, stream>>>(pk, Pbuf, CSbuf);
    combine<<<256, 64, 0, stream>>>(Pbuf, CSbuf, init_st);
    out_scan<<<16 * 4 * NCH, 64, 0, stream>>>(pk, CSbuf, yB);

    gn_bonus<<<T_LEN, 256, 0, stream>>>(yB, rB, kB, vB, gB, r_k, ln_w, ln_b, yg16);
    gemm_bf16<<<dim3(16, 16), 256, 0, stream>>>(yg16, Wo16, out);
}